// Round 14
// baseline (326.120 us; speedup 1.0000x reference)
//
#include <hip/hip_runtime.h>

typedef __bf16 bf16_t;
typedef __bf16 bf16x8 __attribute__((ext_vector_type(8)));
typedef __bf16 bf16x4 __attribute__((ext_vector_type(4)));
typedef float f32x4 __attribute__((ext_vector_type(4)));
typedef float f32x16 __attribute__((ext_vector_type(16)));
typedef short s16x4 __attribute__((ext_vector_type(4)));
typedef short s16x8 __attribute__((ext_vector_type(8)));
typedef unsigned u32x2 __attribute__((ext_vector_type(2)));

#define MFMA16(A_, B_, C_) __builtin_amdgcn_mfma_f32_16x16x32_bf16((A_), (B_), (C_), 0, 0, 0)
#define MFMA32(A_, B_, C_) __builtin_amdgcn_mfma_f32_32x32x16_bf16((A_), (B_), (C_), 0, 0, 0)

// softmax scale folded into Q at GEMM0: 0.125 * log2(e) so p = exp2(s - m)
#define QSC 0.18033688011112042f

// Raw v_exp_f32 (2^x) when available: libm exp2f routes through
// __ocml_exp2_f32 (~6-10 instrs) without fast-math.
#if __has_builtin(__builtin_amdgcn_exp2f)
#define EXP2F(x) __builtin_amdgcn_exp2f(x)
#else
#define EXP2F(x) exp2f(x)
#endif

__device__ __forceinline__ void gload_lds16(const bf16_t* g, bf16_t* l) {
  __builtin_amdgcn_global_load_lds(
      (const __attribute__((address_space(1))) void*)g,
      (__attribute__((address_space(3))) void*)l, 16, 0, 0);
}

__device__ __forceinline__ unsigned cvt_pk_bf16(float a, float b) {
  unsigned r;
  asm("v_cvt_pk_bf16_f32 %0, %1, %2" : "=v"(r) : "v"(a), "v"(b));
  return r;
}

// HW transpose read (attn). Lane l supplies chunk_base + (l&15)*8B and
// receives column (l&15): elem j = chunk[j][l&15] of a 4x16-bf16 tile.
__device__ __forceinline__ s16x4 tr_b16(const bf16_t* p) {
  s16x4 d;
  unsigned off = (unsigned)(size_t)(const __attribute__((address_space(3))) bf16_t*)p;
  asm volatile("ds_read_b64_tr_b16 %0, %1" : "=v"(d) : "v"(off));
  return d;
}

// b128 LDS read as volatile inline asm: no compiler-inserted waits; ordering
// is the explicit vmcnt/lgkmcnt/barrier discipline documented per kernel.
union B128 { s16x8 s; bf16x8 b; };

#define DSR(PTR, U)                                                           \
  do {                                                                        \
    unsigned _o = (unsigned)(size_t)                                          \
        (const __attribute__((address_space(3))) bf16_t*)(PTR);               \
    asm volatile("ds_read_b128 %0, %1" : "=v"((U).s) : "v"(_o));              \
  } while (0)

// exchange: ra[l<32]=b[l+32], ra[l>=32]=a ; rb[l<32]=b, rb[l>=32]=a[l-32]
// v_permlane32_swap_b32 vdst, vsrc: vdst.hi <-> vsrc.lo; intrinsic returns
// {vdst_new, vsrc_new}. Call with (vdst=b, vsrc=a): rb={b.lo,a.lo},
// ra={b.hi,a.hi}. (Verified by round-13 pass.)
__device__ __forceinline__ void swap32(unsigned a, unsigned b, int hi,
                                       unsigned& ra, unsigned& rb) {
#if __has_builtin(__builtin_amdgcn_permlane32_swap)
  u32x2 r = __builtin_amdgcn_permlane32_swap(b, a, false, false);
  rb = r[0]; ra = r[1];
#else
  unsigned bx = (unsigned)__shfl_xor((int)b, 32);
  unsigned ax = (unsigned)__shfl_xor((int)a, 32);
  ra = hi ? a : bx;
  rb = hi ? ax : b;
#endif
}

// fp32 -> bf16, 4 elements/thread
__global__ __launch_bounds__(256) void k_convert(const float* __restrict__ in,
                                                 bf16_t* __restrict__ out, int n4) {
  int i = blockIdx.x * 256 + threadIdx.x;
  if (i >= n4) return;
  float4 v = ((const float4*)in)[i];
  bf16x4 o;
  o[0] = (__bf16)v.x; o[1] = (__bf16)v.y; o[2] = (__bf16)v.z; o[3] = (__bf16)v.w;
  *(bf16x4*)(out + (size_t)i * 4) = o;
}

// out[c][r] = (bf16) in[r][c];  in is [R][C] fp32. 64x64 tiles, 256 threads.
__global__ __launch_bounds__(256) void k_transpose(const float* __restrict__ in,
                                                   bf16_t* __restrict__ out, int R, int C) {
  __shared__ float tile[64][65];
  int tx = threadIdx.x & 63;
  int ty = threadIdx.x >> 6;
  int bc = blockIdx.x * 64;
  int br = blockIdx.y * 64;
#pragma unroll
  for (int i = ty; i < 64; i += 4)
    tile[i][tx] = in[(size_t)(br + i) * C + bc + tx];
  __syncthreads();
#pragma unroll
  for (int i = ty; i < 64; i += 4)
    out[(size_t)(bc + i) * R + br + tx] = (bf16_t)tile[tx][i];
}

// block-split row permutation: original token row -> attention-layout row
__device__ __forceinline__ int permrow(int r) {
  int b  = r >> 12;
  int l  = r & 4095;
  int ix = (l >> 11) & 1;
  int sx = (l >> 6) & 31;
  int iy = (l >> 5) & 1;
  int sy = l & 31;
  return (b << 12) + (ix << 11) + (iy << 10) + (sx << 5) + sy;
}

#define SBAR __builtin_amdgcn_sched_barrier(0)

// ---------------------------------------------------------------------------
// k_gemmA round-14: UNLOCKSTEPPED 1-barrier-per-K-tile loop (was 2 phases x
// 2 barriers). 256x128 tile, grid 768 = 3 clean waves, ring-3 LDS, 8 waves
// of 64x64. Iter t: [vmcnt(6); s_barrier; reads(t) 16xb128; stage(t+2) 6x
// gload_lds; lgkmcnt(0); MFMA(t) 32]. Waves de-phase after the barrier so
// wave A's MFMA overlaps wave B's DS drain (the old lockstep serialized
// DS and MFMA chip-wide: 1536+1242 cyc/K-tile; overlap floor = max() ~1.8k).
// Vmcnt ledger (per wave, 6 issues/K-tile): prologue stages t0,t1 (12 out);
// iter t top: outstanding = stage(t)[6] + stage(t+1)[6] = 12; vmcnt(6)
// retires stage(t); barrier then makes ALL waves' stage(t) visible -> reads
// safe (RAW). WAR: stage(t+2) (issued after bar(t)) overwrites slot
// (t-1)%3; every wave's reads(t-1) completed at its lgkm0 in iter t-1,
// before bar(t). Epilogue t2-clamp restages tile 31 (slot unread, ledger
// intact).
// ---------------------------------------------------------------------------
#define LA(K_) (lds + (K_)*24576)
#define LB(K_) (lds + (K_)*24576 + 16384)

__global__ __launch_bounds__(512, 2) void k_gemmA(
    const bf16_t* __restrict__ A,
    const bf16_t* __restrict__ B0, const bf16_t* __restrict__ B1,
    const bf16_t* __restrict__ B2,
    bf16_t* __restrict__ Cq, bf16_t* __restrict__ Ck, bf16_t* __restrict__ Cv) {
  extern __shared__ bf16_t lds[];

  int bid = blockIdx.x;
  int s = bid >> 3;                 // 0..95
  int tm = (bid & 7) * 4 + s / 24;  // 0..31 (256-row tiles)
  int tn = s % 24;                  // 0..23 (128-col tiles)

  const bf16_t* Bp;
  int brow;
  if (tn < 16)      { Bp = B0; brow = tn << 7; }
  else if (tn < 20) { Bp = B1; brow = (tn - 16) << 7; }
  else              { Bp = B2; brow = (tn - 20) << 7; }

  int tid = threadIdx.x;
  int lane = tid & 63;
  int w = tid >> 6;                  // 0..7
  int wm = w >> 1, wn = w & 1;       // 4M x 2N wave grid
  int g16 = lane >> 4, cl = lane & 15;
  int swz8 = (cl & 7) << 3;
  int wofs = w << 9;

  int srow = tid >> 3;                                  // 0..63
  int lc = (((tid & 7) ^ (srow & 7)) << 3);             // pre-swizzled col
  const bf16_t* aB = A + (size_t)(tm * 256 + srow) * 2048 + lc;
  const bf16_t* bB = Bp + (size_t)(brow + srow) * 2048 + lc;

#define GA_STAGE_A(K_, T_)                                                     \
  _Pragma("unroll") for (int rr = 0; rr < 4; ++rr)                             \
    gload_lds16(aB + (size_t)(rr * 64) * 2048 + (T_)*64,                       \
                LA(K_) + rr * 4096 + wofs);

#define GA_STAGE_B(K_, T_)                                                     \
  _Pragma("unroll") for (int rr = 0; rr < 2; ++rr)                             \
    gload_lds16(bB + (size_t)(rr * 64) * 2048 + (T_)*64,                       \
                LB(K_) + rr * 4096 + wofs);

#define GA_RD_B(K_)                                                            \
  _Pragma("unroll") for (int ni = 0; ni < 4; ++ni) {                           \
    const bf16_t* Br = LB(K_) + (wn * 64 + ni * 16 + cl) * 64;                 \
    DSR(Br + ((g16 * 8) ^ swz8), bfr[ni][0]);                                  \
    DSR(Br + ((32 + g16 * 8) ^ swz8), bfr[ni][1]);                             \
  }

#define GA_RD_A4(K_)                                                           \
  _Pragma("unroll") for (int m = 0; m < 4; ++m) {                              \
    const bf16_t* Ar = LA(K_) + (wm * 64 + m * 16 + cl) * 64;                  \
    DSR(Ar + ((g16 * 8) ^ swz8), af[m][0]);                                    \
    DSR(Ar + ((32 + g16 * 8) ^ swz8), af[m][1]);                               \
  }

#define GA_MFMA_ALL                                                            \
  _Pragma("unroll") for (int kk = 0; kk < 2; ++kk)                             \
    _Pragma("unroll") for (int m = 0; m < 4; ++m)                              \
      _Pragma("unroll") for (int ni = 0; ni < 4; ++ni)                         \
        acc[m][ni] = MFMA16(af[m][kk].b, bfr[ni][kk].b, acc[m][ni]);

  f32x4 acc[4][4];
#pragma unroll
  for (int i = 0; i < 4; ++i)
#pragma unroll
    for (int j = 0; j < 4; ++j) acc[i][j] = (f32x4)(0.0f);

  // prologue: stage tiles 0,1 (12 issues/wave)
  GA_STAGE_A(0, 0); GA_STAGE_B(0, 0);
  GA_STAGE_A(1, 1); GA_STAGE_B(1, 1);

  int k = 0;
  for (int t = 0; t < 32; ++t) {
    int k2 = k + 2; if (k2 >= 3) k2 -= 3;
    int t2 = t + 2; if (t2 > 31) t2 = 31;  // clamped: slot unread after loop
    B128 af[4][2], bfr[4][2];
    asm volatile("s_waitcnt vmcnt(6)" ::: "memory");
    __builtin_amdgcn_s_barrier();
    GA_RD_B(k); GA_RD_A4(k);
    GA_STAGE_A(k2, t2); GA_STAGE_B(k2, t2);
    asm volatile("s_waitcnt lgkmcnt(0)" ::: "memory");
    SBAR;
    __builtin_amdgcn_s_setprio(1);
    GA_MFMA_ALL;
    __builtin_amdgcn_s_setprio(0);
    ++k; if (k == 3) k = 0;
  }

#pragma unroll
  for (int mi = 0; mi < 4; ++mi) {
#pragma unroll
    for (int rr = 0; rr < 4; ++rr) {
      int r = tm * 256 + wm * 64 + mi * 16 + g16 * 4 + rr;
      int rp = permrow(r);
#pragma unroll
      for (int ni = 0; ni < 4; ++ni) {
        int c = tn * 128 + wn * 64 + ni * 16 + cl;
        float v = acc[mi][ni][rr];
        if (c < 2048)      Cq[(size_t)rp * 2048 + c] = (bf16_t)(v * QSC);
        else if (c < 2560) Ck[(size_t)rp * 512 + (c - 2048)] = (bf16_t)v;
        else               Cv[(size_t)rp * 512 + (c - 2560)] = (bf16_t)v;
      }
    }
  }
}

// ---------------------------------------------------------------------------
// k_gemmB: unchanged from round 10 (round-7 8-phase 256x256 body, locality
// XCD map, grid 256 = 1 clean wave).
// ---------------------------------------------------------------------------
#define LSLOT(B_, M_, H_) (lds + (((B_)*4 + (M_)*2 + (H_)) << 13))

#define STAGE_A(BUF, HF, T)                                                     \
  gload_lds16(aB + (size_t)((HF)*128) * 2048 + (T)*64, LSLOT(BUF, 0, HF) + wofs); \
  gload_lds16(aB + (size_t)((HF)*128 + 64) * 2048 + (T)*64,                     \
              LSLOT(BUF, 0, HF) + wofs + 4096);

#define STAGE_B(BUF, HF, T)                                                     \
  gload_lds16(bB + (size_t)((HF)*128) * 2048 + (T)*64, LSLOT(BUF, 1, HF) + wofs); \
  gload_lds16(bB + (size_t)((HF)*128 + 64) * 2048 + (T)*64,                     \
              LSLOT(BUF, 1, HF) + wofs + 4096);

#define LOAD_A(BUF, Q)                                                          \
  { const bf16_t* Ah = LSLOT(BUF, 0, wm) + ((Q)*32 + cl) * 64;                  \
    DSR(Ah + ((g16 * 8) ^ swz8), af[0][0]);                                     \
    DSR(Ah + ((32 + g16 * 8) ^ swz8), af[0][1]);                                \
    DSR(Ah + 1024 + ((g16 * 8) ^ swz8), af[1][0]);                              \
    DSR(Ah + 1024 + ((32 + g16 * 8) ^ swz8), af[1][1]); }

#define LOAD_B(BUF)                                                             \
  { const bf16_t* Bh = LSLOT(BUF, 1, wn >> 1);                                  \
    _Pragma("unroll") for (int ni = 0; ni < 4; ++ni) {                          \
      const bf16_t* Br = Bh + ((wn & 1) * 64 + ni * 16 + cl) * 64;              \
      DSR(Br + ((g16 * 8) ^ swz8), bfr[ni][0]);                                 \
      DSR(Br + ((32 + g16 * 8) ^ swz8), bfr[ni][1]); } }

#define MFMA_QUAD(Q)                                                            \
  _Pragma("unroll") for (int kk = 0; kk < 2; ++kk)                              \
    _Pragma("unroll") for (int ni = 0; ni < 4; ++ni) {                          \
      acc[2*(Q)][ni]   = MFMA16(af[0][kk].b, bfr[ni][kk].b, acc[2*(Q)][ni]);    \
      acc[2*(Q)+1][ni] = MFMA16(af[1][kk].b, bfr[ni][kk].b, acc[2*(Q)+1][ni]); }

#define PH_MID(VM4)                                                             \
  if (VM4) asm volatile("s_waitcnt vmcnt(4)" ::: "memory");                     \
  __builtin_amdgcn_s_barrier();                                                 \
  asm volatile("s_waitcnt lgkmcnt(0)" ::: "memory");                            \
  SBAR;                                                                         \
  __builtin_amdgcn_s_setprio(1);

#define PH_END                                                                  \
  SBAR;                                                                         \
  __builtin_amdgcn_s_setprio(0);                                                \
  __builtin_amdgcn_s_barrier();

__global__ __launch_bounds__(512, 2) void k_gemmB(
    const bf16_t* __restrict__ A, const bf16_t* __restrict__ B0,
    float* __restrict__ Cf) {
  extern __shared__ bf16_t lds[];

  int bid = blockIdx.x;
  int s = bid >> 3;                 // 0..31
  int tm = (bid & 7) * 4 + (s >> 3);
  int tn = s & 7;
  const bf16_t* Bp = B0;
  int brow = tn << 8;

  int tid = threadIdx.x;
  int lane = tid & 63;
  int w = tid >> 6;
  int wm = w >> 2, wn = w & 3;
  int g16 = lane >> 4, cl = lane & 15;
  int swz8 = (cl & 7) << 3;
  int wofs = w << 9;

  int srow = tid >> 3;
  int lc = (((tid & 7) ^ (srow & 7)) << 3);
  const bf16_t* aB = A + (size_t)(tm * 256 + srow) * 2048 + lc;
  const bf16_t* bB = Bp + (size_t)(brow + srow) * 2048 + lc;

  f32x4 acc[8][4];
#pragma unroll
  for (int i = 0; i < 8; ++i)
#pragma unroll
    for (int j = 0; j < 4; ++j) acc[i][j] = (f32x4)(0.0f);

  STAGE_A(0, 0, 0); STAGE_A(0, 1, 0);
  STAGE_B(0, 0, 0); STAGE_B(0, 1, 0);
  STAGE_B(1, 0, 1); STAGE_B(1, 1, 1);
  asm volatile("s_waitcnt vmcnt(4)" ::: "memory");
  __builtin_amdgcn_s_barrier();

  for (int it2 = 0; it2 < 16; ++it2) {
    int t1 = 2 * it2 + 1;
    int tf = 2 * it2 + 2; if (tf > 31) tf = 31;
    int tg = 2 * it2 + 3; if (tg > 31) tg = 31;
    B128 af[2][2], bfr[4][2];
    STAGE_A(1, 0, t1);
    LOAD_B(0); LOAD_A(0, 0);
    PH_MID(0); MFMA_QUAD(0); PH_END;
    STAGE_A(1, 1, t1);
    LOAD_A(0, 1);
    PH_MID(0); MFMA_QUAD(1); PH_END;
    STAGE_B(0, 0, tf);
    LOAD_A(0, 2);
    PH_MID(0); MFMA_QUAD(2); PH_END;
    STAGE_B(0, 1, tf);
    LOAD_A(0, 3);
    PH_MID(1); MFMA_QUAD(3); PH_END;
    STAGE_A(0, 0, tf);
    LOAD_B(1); LOAD_A(1, 0);
    PH_MID(0); MFMA_QUAD(0); PH_END;
    STAGE_A(0, 1, tf);
    LOAD_A(1, 1);
    PH_MID(0); MFMA_QUAD(1); PH_END;
    STAGE_B(1, 0, tg);
    LOAD_A(1, 2);
    PH_MID(0); MFMA_QUAD(2); PH_END;
    STAGE_B(1, 1, tg);
    LOAD_A(1, 3);
    PH_MID(1); MFMA_QUAD(3); PH_END;
  }

#pragma unroll
  for (int mi = 0; mi < 8; ++mi) {
#pragma unroll
    for (int rr = 0; rr < 4; ++rr) {
      int r = tm * 256 + wm * 128 + mi * 16 + g16 * 4 + rr;
#pragma unroll
      for (int ni = 0; ni < 4; ++ni) {
        int c = tn * 256 + wn * 64 + ni * 16 + cl;
        Cf[(size_t)r * 2048 + c] = acc[mi][ni][rr];
      }
    }
  }
}

// m214-style swapped-QK^T flash attention (round-13 body, unchanged).
__global__ __launch_bounds__(256, 2) void k_attn(
    const bf16_t* __restrict__ Qp, const bf16_t* __restrict__ Kp,
    const bf16_t* __restrict__ Vp, bf16_t* __restrict__ O) {
  int bid = blockIdx.x;
  int qc = bid & 7;
  int h  = (bid >> 3) & 31;
  int n  = bid >> 8;
  int kvh = h >> 2;

  __shared__ bf16_t buf[2][8192];

  int tid = threadIdx.x, lane = tid & 63, w = tid >> 6;
  int l31 = lane & 31, hi = lane >> 5;
  int qrow_blk = n * 1024 + qc * 128;
  bf16_t* base = &buf[0][0];

#pragma unroll
  for (int r = 0; r < 4; ++r) {
    int ql = r * 32 + (tid >> 3);
    int cs = (tid & 7) << 4;
    int lc = (cs ^ ((ql & 7) << 4)) >> 1;
    gload_lds16(Qp + (size_t)(qrow_blk + ql) * 2048 + h * 64 + lc,
                base + r * 2048 + w * 512);
  }
  __syncthreads();
  bf16x8 qf[4];
  {
    int q = w * 32 + l31;
    const bf16_t* qrow = base + q * 64;
    int sw = (q & 7) << 4;
#pragma unroll
    for (int c = 0; c < 4; ++c)
      qf[c] = *(const bf16x8*)(qrow + (((c * 32 + hi * 16) ^ sw) >> 1));
  }
  __syncthreads();

  f32x16 oacc0 = (f32x16)(0.0f), oacc1 = (f32x16)(0.0f);
  float m_run = -1e30f, l_run = 0.0f;

  auto stageKV = [&](int t) {
    bf16_t* bp = &buf[t & 1][0];
    int kvb = n * 1024 + t * 64;
#pragma unroll
    for (int r = 0; r < 2; ++r) {
      int kv = r * 32 + (tid >> 3);
      int cs = (tid & 7) << 4;
      int lc = (cs ^ ((kv & 7) << 4)) >> 1;
      gload_lds16(Kp + (size_t)(kvb + kv) * 512 + kvh * 64 + lc,
                  bp + r * 2048 + w * 512);
    }
#pragma unroll
    for (int r = 0; r < 2; ++r) {
      int slot = r * 256 + tid;
      int sub = slot >> 3;
      int kb = sub >> 2, db = sub & 3;
      int j = (slot >> 1) & 3, hf = slot & 1;
      gload_lds16(Vp + (size_t)(kvb + kb * 4 + j) * 512 + kvh * 64 + db * 16 + hf * 8,
                  bp + 4096 + r * 2048 + w * 512);
    }
  };

  stageKV(0);
  for (int t = 0; t < 16; ++t) {
    __syncthreads();
    if (t < 15) stageKV(t + 1);
    const bf16_t* bp = &buf[t & 1][0];
    const bf16_t* Vs = bp + 4096;

#pragma unroll
    for (int s = 0; s < 2; ++s) {
      f32x16 st = (f32x16)(0.0f);
      {
        int kv = s * 32 + l31;
        const bf16_t* krow = bp + kv * 64;
        int sw = (kv & 7) << 4;
#pragma unroll
        for (int c = 0; c < 4; ++c) {
          bf16x8 kf = *(const bf16x8*)(krow + (((c * 32 + hi * 16) ^ sw) >> 1));
          st = MFMA32(kf, qf[c], st);
        }
      }
      // pmax via v_max3-friendly nesting: 5 triples + 2 triples + 1 max
      float p0 = fmaxf(fmaxf(st[0], st[1]), st[2]);
      float p1 = fmaxf(fmaxf(st[3], st[4]), st[5]);
      float p2 = fmaxf(fmaxf(st[6], st[7]), st[8]);
      float p3 = fmaxf(fmaxf(st[9], st[10]), st[11]);
      float p4 = fmaxf(fmaxf(st[12], st[13]), st[14]);
      float pmax = fmaxf(fmaxf(fmaxf(p0, p1), p2),
                         fmaxf(fmaxf(p3, p4), st[15]));
      pmax = fmaxf(pmax, __shfl_xor(pmax, 32));
      if (!__all(pmax <= m_run + 11.0f)) {
        float mnew = fmaxf(m_run, pmax);
        float resc = EXP2F(m_run - mnew);
        l_run *= resc;
#pragma unroll
        for (int e = 0; e < 16; ++e) { oacc0[e] *= resc; oacc1[e] *= resc; }
        m_run = mnew;
      }
      float rs = 0.0f;
      unsigned pw[8];
#pragma unroll
      for (int u = 0; u < 8; ++u) {
        float q0 = EXP2F(st[2 * u] - m_run);
        float q1 = EXP2F(st[2 * u + 1] - m_run);
        rs += q0 + q1;
        pw[u] = cvt_pk_bf16(q0, q1);
      }
      rs += __shfl_xor(rs, 32);
      l_run += rs;

#pragma unroll
      for (int c = 0; c < 2; ++c) {
        unsigned w2, w0, w3, w1;
        swap32(pw[c * 4 + 2], pw[c * 4 + 0], hi, w2, w0);
        swap32(pw[c * 4 + 3], pw[c * 4 + 1], hi, w3, w1);
        union { unsigned u[4]; bf16x8 v; } pa;
        pa.u[0] = w0; pa.u[1] = w1; pa.u[2] = w2; pa.u[3] = w3;
        int kb0 = s * 8 + c * 4 + hi * 2;
        int dbl = l31 >> 4;
        int cc8 = (l31 & 15) * 4;
        const bf16_t* p00 = Vs + (kb0 * 4 + dbl) * 64 + cc8;
        const bf16_t* p01 = Vs + ((kb0 + 1) * 4 + dbl) * 64 + cc8;
        const bf16_t* p10 = Vs + (kb0 * 4 + 2 + dbl) * 64 + cc8;
        const bf16_t* p11 = Vs + ((kb0 + 1) * 4 + 2 + dbl) * 64 + cc8;
        s16x4 t00 = tr_b16(p00), t01 = tr_b16(p01);
        s16x4 t10 = tr_b16(p10), t11 = tr_b16(p11);
        asm volatile("s_waitcnt lgkmcnt(0)" ::: "memory");
        __builtin_amdgcn_sched_barrier(0);
        union { s16x4 s4[2]; bf16x8 v; } vf0, vf1;
        vf0.s4[0] = t00; vf0.s4[1] = t01;
        vf1.s4[0] = t10; vf1.s4[1] = t11;
        oacc0 = MFMA32(pa.v, vf0.v, oacc0);
        oacc1 = MFMA32(pa.v, vf1.v, oacc1);
      }
    }
  }

  float linv = 1.0f / l_run;
#pragma unroll
  for (int r = 0; r < 16; ++r) {
    int qrw = (r & 3) + 8 * (r >> 2) + 4 * hi;
    float li = __shfl(linv, qrw);
    size_t orow = (size_t)(qrow_blk + w * 32 + qrw) * 2048 + h * 64 + l31;
    O[orow]      = (bf16_t)(oacc0[r] * li);
    O[orow + 32] = (bf16_t)(oacc1[r] * li);
  }
}

extern "C" void kernel_launch(void* const* d_in, const int* in_sizes, int n_in,
                              void* d_out, int out_size, void* d_ws, size_t ws_size,
                              hipStream_t stream) {
  const float* X  = (const float*)d_in[0];
  const float* Wq = (const float*)d_in[1];
  const float* Wk = (const float*)d_in[2];
  const float* Wv = (const float*)d_in[3];
  const float* Wo = (const float*)d_in[4];
  float* out = (float*)d_out;

  char* ws = (char*)d_ws;
  const size_t MB = 1024 * 1024;
  bf16_t* Xb  = (bf16_t*)(ws + 0);
  bf16_t* WqT = (bf16_t*)(ws + 32 * MB);
  bf16_t* WkT = (bf16_t*)(ws + 40 * MB);
  bf16_t* WvT = (bf16_t*)(ws + 42 * MB);
  bf16_t* WoT = (bf16_t*)(ws + 44 * MB);
  bf16_t* Qp  = (bf16_t*)(ws + 52 * MB);
  bf16_t* Kp  = (bf16_t*)(ws + 84 * MB);
  bf16_t* Vp  = (bf16_t*)(ws + 92 * MB);
  bf16_t* Ob  = (bf16_t*)(ws + 100 * MB);

  hipFuncSetAttribute(reinterpret_cast<const void*>(&k_gemmA),
                      hipFuncAttributeMaxDynamicSharedMemorySize, 147456);
  hipFuncSetAttribute(reinterpret_cast<const void*>(&k_gemmB),
                      hipFuncAttributeMaxDynamicSharedMemorySize, 131072);

  k_convert<<<16384, 256, 0, stream>>>(X, Xb, 4194304);
  k_transpose<<<dim3(32, 32), 256, 0, stream>>>(Wq, WqT, 2048, 2048);
  k_transpose<<<dim3(8, 32), 256, 0, stream>>>(Wk, WkT, 2048, 512);
  k_transpose<<<dim3(8, 32), 256, 0, stream>>>(Wv, WvT, 2048, 512);
  k_transpose<<<dim3(32, 32), 256, 0, stream>>>(Wo, WoT, 2048, 2048);

  k_gemmA<<<768, 512, 147456, stream>>>(Xb, WqT, WkT, WvT, Qp, Kp, Vp);
  k_attn<<<2048, 256, 0, stream>>>(Qp, Kp, Vp, Ob);
  k_gemmB<<<256, 512, 131072, stream>>>(Ob, WoT, out);
}

// Round 15
// 320.591 us; speedup vs baseline: 1.0172x; 1.0172x over previous
//
#include <hip/hip_runtime.h>

typedef __bf16 bf16_t;
typedef __bf16 bf16x8 __attribute__((ext_vector_type(8)));
typedef __bf16 bf16x4 __attribute__((ext_vector_type(4)));
typedef float f32x4 __attribute__((ext_vector_type(4)));
typedef float f32x16 __attribute__((ext_vector_type(16)));
typedef short s16x4 __attribute__((ext_vector_type(4)));
typedef short s16x8 __attribute__((ext_vector_type(8)));
typedef unsigned u32x2 __attribute__((ext_vector_type(2)));

#define MFMA16(A_, B_, C_) __builtin_amdgcn_mfma_f32_16x16x32_bf16((A_), (B_), (C_), 0, 0, 0)
#define MFMA32(A_, B_, C_) __builtin_amdgcn_mfma_f32_32x32x16_bf16((A_), (B_), (C_), 0, 0, 0)

// softmax scale folded into Q at GEMM0: 0.125 * log2(e) so p = exp2(s - m)
#define QSC 0.18033688011112042f

#if __has_builtin(__builtin_amdgcn_exp2f)
#define EXP2F(x) __builtin_amdgcn_exp2f(x)
#else
#define EXP2F(x) exp2f(x)
#endif

__device__ __forceinline__ void gload_lds16(const bf16_t* g, bf16_t* l) {
  __builtin_amdgcn_global_load_lds(
      (const __attribute__((address_space(1))) void*)g,
      (__attribute__((address_space(3))) void*)l, 16, 0, 0);
}

__device__ __forceinline__ unsigned cvt_pk_bf16(float a, float b) {
  unsigned r;
  asm("v_cvt_pk_bf16_f32 %0, %1, %2" : "=v"(r) : "v"(a), "v"(b));
  return r;
}

// HW transpose read (attn). Lane l supplies chunk_base + (l&15)*8B and
// receives column (l&15): elem j = chunk[j][l&15] of a 4x16-bf16 tile.
__device__ __forceinline__ s16x4 tr_b16(const bf16_t* p) {
  s16x4 d;
  unsigned off = (unsigned)(size_t)(const __attribute__((address_space(3))) bf16_t*)p;
  asm volatile("ds_read_b64_tr_b16 %0, %1" : "=v"(d) : "v"(off));
  return d;
}

// b128 LDS read as volatile inline asm: no compiler-inserted waits; ordering
// is the explicit vmcnt/lgkmcnt/barrier discipline documented per kernel.
union B128 { s16x8 s; bf16x8 b; };

#define DSR(PTR, U)                                                           \
  do {                                                                        \
    unsigned _o = (unsigned)(size_t)                                          \
        (const __attribute__((address_space(3))) bf16_t*)(PTR);               \
    asm volatile("ds_read_b128 %0, %1" : "=v"((U).s) : "v"(_o));              \
  } while (0)

// b128 read from hoisted base REGISTER + 16-bit immediate offset (string
// literal). With unroll-3 ring, all gemmA fragment addresses reduce to
// 12 loop-invariant per-lane bases + these immediates -> zero in-loop VALU.
#define DSR_OFS(BASEV, OFFSTR, U)                                             \
  asm volatile("ds_read_b128 %0, %1 offset:" OFFSTR                           \
               : "=v"((U).s) : "v"(BASEV))

// exchange: ra[l<32]=b[l+32], ra[l>=32]=a ; rb[l<32]=b, rb[l>=32]=a[l-32]
// v_permlane32_swap_b32(vdst=b, vsrc=a): rb={b.lo,a.lo}, ra={b.hi,a.hi}.
__device__ __forceinline__ void swap32(unsigned a, unsigned b, int hi,
                                       unsigned& ra, unsigned& rb) {
#if __has_builtin(__builtin_amdgcn_permlane32_swap)
  u32x2 r = __builtin_amdgcn_permlane32_swap(b, a, false, false);
  rb = r[0]; ra = r[1];
#else
  unsigned bx = (unsigned)__shfl_xor((int)b, 32);
  unsigned ax = (unsigned)__shfl_xor((int)a, 32);
  ra = hi ? a : bx;
  rb = hi ? ax : b;
#endif
}

// fp32 -> bf16, 4 elements/thread
__global__ __launch_bounds__(256) void k_convert(const float* __restrict__ in,
                                                 bf16_t* __restrict__ out, int n4) {
  int i = blockIdx.x * 256 + threadIdx.x;
  if (i >= n4) return;
  float4 v = ((const float4*)in)[i];
  bf16x4 o;
  o[0] = (__bf16)v.x; o[1] = (__bf16)v.y; o[2] = (__bf16)v.z; o[3] = (__bf16)v.w;
  *(bf16x4*)(out + (size_t)i * 4) = o;
}

// out[c][r] = (bf16) in[r][c];  in is [R][C] fp32. 64x64 tiles, 256 threads.
__global__ __launch_bounds__(256) void k_transpose(const float* __restrict__ in,
                                                   bf16_t* __restrict__ out, int R, int C) {
  __shared__ float tile[64][65];
  int tx = threadIdx.x & 63;
  int ty = threadIdx.x >> 6;
  int bc = blockIdx.x * 64;
  int br = blockIdx.y * 64;
#pragma unroll
  for (int i = ty; i < 64; i += 4)
    tile[i][tx] = in[(size_t)(br + i) * C + bc + tx];
  __syncthreads();
#pragma unroll
  for (int i = ty; i < 64; i += 4)
    out[(size_t)(bc + i) * R + br + tx] = (bf16_t)tile[tx][i];
}

// block-split row permutation: original token row -> attention-layout row
__device__ __forceinline__ int permrow(int r) {
  int b  = r >> 12;
  int l  = r & 4095;
  int ix = (l >> 11) & 1;
  int sx = (l >> 6) & 31;
  int iy = (l >> 5) & 1;
  int sy = l & 31;
  return (b << 12) + (ix << 11) + (iy << 10) + (sx << 5) + sy;
}

#define SBAR __builtin_amdgcn_sched_barrier(0)

// ---------------------------------------------------------------------------
// k_gemmA round-15: round-14 un-lockstepped loop + UNROLL-3 ring with
// immediate-offset ds_reads. Profile showed VALUBusy 21.6% (~730 cyc/K-tile)
// = per-iteration address recompute for runtime ring indices. Now: 12
// hoisted per-lane LDS bases (A/B x kk0/kk1 x 3 slots), fragment reads are
// ds_read_b128 base offset:{0,2048,4096,6144}; staging uses 2 running global
// pointers (+64 elem/tile). Ledger (per wave, 6 issues/K-tile): prologue
// stages t0,t1 (12 out). Body t: vmcnt(6) retires stage(t); barrier -> all
// waves' stage(t) visible (RAW); reads(slot t%3); stage(t+2) into slot
// (t+2)%3 (WAR: that slot's reads finished before each wave's lgkm0 in
// iter t-1, which precedes this barrier); lgkm0; MFMA. Tail: t=30 vmcnt(6)
// no-stage; t=31 vmcnt(0) no-stage.
// ---------------------------------------------------------------------------
#define LA(K_) (lds + (K_)*24576)
#define LB(K_) (lds + (K_)*24576 + 16384)

__global__ __launch_bounds__(512, 2) void k_gemmA(
    const bf16_t* __restrict__ A,
    const bf16_t* __restrict__ B0, const bf16_t* __restrict__ B1,
    const bf16_t* __restrict__ B2,
    bf16_t* __restrict__ Cq, bf16_t* __restrict__ Ck, bf16_t* __restrict__ Cv) {
  extern __shared__ bf16_t lds[];

  int bid = blockIdx.x;
  int s = bid >> 3;                 // 0..95
  int tm = (bid & 7) * 4 + s / 24;  // 0..31 (256-row tiles)
  int tn = s % 24;                  // 0..23 (128-col tiles)

  const bf16_t* Bp;
  int brow;
  if (tn < 16)      { Bp = B0; brow = tn << 7; }
  else if (tn < 20) { Bp = B1; brow = (tn - 16) << 7; }
  else              { Bp = B2; brow = (tn - 20) << 7; }

  int tid = threadIdx.x;
  int lane = tid & 63;
  int w = tid >> 6;                  // 0..7
  int wm = w >> 1, wn = w & 1;       // 4M x 2N wave grid
  int g16 = lane >> 4, cl = lane & 15;
  int swz8 = (cl & 7) << 3;
  int wofs = w << 9;

  int srow = tid >> 3;                                  // 0..63
  int lc = (((tid & 7) ^ (srow & 7)) << 3);             // pre-swizzled col
  const bf16_t* aBt = A + (size_t)(tm * 256 + srow) * 2048 + lc;
  const bf16_t* bBt = Bp + (size_t)(brow + srow) * 2048 + lc;

  // 12 loop-invariant per-lane LDS base byte-addresses
  unsigned ldsb = (unsigned)(size_t)(__attribute__((address_space(3))) bf16_t*)lds;
  unsigned arow0 = (unsigned)((wm * 64 + cl) * 128 + (((g16 * 8) ^ swz8) << 1));
  unsigned arow1 = (unsigned)((wm * 64 + cl) * 128 + ((((32 + g16 * 8)) ^ swz8) << 1));
  unsigned brow0 = (unsigned)(32768 + (wn * 64 + cl) * 128 + (((g16 * 8) ^ swz8) << 1));
  unsigned brow1 = (unsigned)(32768 + (wn * 64 + cl) * 128 + ((((32 + g16 * 8)) ^ swz8) << 1));
  unsigned a0[3], a1[3], b0[3], b1[3];
#pragma unroll
  for (int kk = 0; kk < 3; ++kk) {
    a0[kk] = ldsb + kk * 49152 + arow0;
    a1[kk] = ldsb + kk * 49152 + arow1;
    b0[kk] = ldsb + kk * 49152 + brow0;
    b1[kk] = ldsb + kk * 49152 + brow1;
  }

#define GA_STAGE(K2_)                                                          \
  _Pragma("unroll") for (int rr = 0; rr < 4; ++rr)                             \
    gload_lds16(aBt + (size_t)(rr * 64) * 2048, LA(K2_) + rr * 4096 + wofs);   \
  _Pragma("unroll") for (int rr = 0; rr < 2; ++rr)                             \
    gload_lds16(bBt + (size_t)(rr * 64) * 2048, LB(K2_) + rr * 4096 + wofs);   \
  aBt += 64; bBt += 64;

#define GA_MFMA_ALL                                                            \
  _Pragma("unroll") for (int kk = 0; kk < 2; ++kk)                             \
    _Pragma("unroll") for (int m = 0; m < 4; ++m)                              \
      _Pragma("unroll") for (int ni = 0; ni < 4; ++ni)                         \
        acc[m][ni] = MFMA16(af[m][kk].b, bfr[ni][kk].b, acc[m][ni]);

#define GA_BODY(K_, K2_, VMSTR_, DOSTAGE_)                                     \
  {                                                                            \
    B128 af[4][2], bfr[4][2];                                                  \
    asm volatile("s_waitcnt vmcnt(" VMSTR_ ")" ::: "memory");                  \
    __builtin_amdgcn_s_barrier();                                              \
    DSR_OFS(b0[K_], "0",    bfr[0][0]); DSR_OFS(b0[K_], "2048", bfr[1][0]);    \
    DSR_OFS(b0[K_], "4096", bfr[2][0]); DSR_OFS(b0[K_], "6144", bfr[3][0]);    \
    DSR_OFS(b1[K_], "0",    bfr[0][1]); DSR_OFS(b1[K_], "2048", bfr[1][1]);    \
    DSR_OFS(b1[K_], "4096", bfr[2][1]); DSR_OFS(b1[K_], "6144", bfr[3][1]);    \
    DSR_OFS(a0[K_], "0",    af[0][0]);  DSR_OFS(a0[K_], "2048", af[1][0]);     \
    DSR_OFS(a0[K_], "4096", af[2][0]);  DSR_OFS(a0[K_], "6144", af[3][0]);     \
    DSR_OFS(a1[K_], "0",    af[0][1]);  DSR_OFS(a1[K_], "2048", af[1][1]);     \
    DSR_OFS(a1[K_], "4096", af[2][1]);  DSR_OFS(a1[K_], "6144", af[3][1]);     \
    if (DOSTAGE_) { GA_STAGE(K2_); }                                           \
    asm volatile("s_waitcnt lgkmcnt(0)" ::: "memory");                         \
    SBAR;                                                                      \
    __builtin_amdgcn_s_setprio(1);                                             \
    GA_MFMA_ALL;                                                               \
    __builtin_amdgcn_s_setprio(0);                                             \
  }

  f32x4 acc[4][4];
#pragma unroll
  for (int i = 0; i < 4; ++i)
#pragma unroll
    for (int j = 0; j < 4; ++j) acc[i][j] = (f32x4)(0.0f);

  // prologue: stage tiles 0 (slot 0) and 1 (slot 1); 12 issues/wave
  GA_STAGE(0);
  GA_STAGE(1);

  for (int t3 = 0; t3 < 30; t3 += 3) {
    GA_BODY(0, 2, "6", 1);   // t = t3:   slot 0, stage t3+2 -> slot 2
    GA_BODY(1, 0, "6", 1);   // t = t3+1: slot 1, stage t3+3 -> slot 0
    GA_BODY(2, 1, "6", 1);   // t = t3+2: slot 2, stage t3+4 -> slot 1
  }
  GA_BODY(0, 2, "6", 0);     // t = 30: slot 0, no stage
  GA_BODY(1, 0, "0", 0);     // t = 31: slot 1, drain

#pragma unroll
  for (int mi = 0; mi < 4; ++mi) {
#pragma unroll
    for (int rr = 0; rr < 4; ++rr) {
      int r = tm * 256 + wm * 64 + mi * 16 + g16 * 4 + rr;
      int rp = permrow(r);
#pragma unroll
      for (int ni = 0; ni < 4; ++ni) {
        int c = tn * 128 + wn * 64 + ni * 16 + cl;
        float v = acc[mi][ni][rr];
        if (c < 2048)      Cq[(size_t)rp * 2048 + c] = (bf16_t)(v * QSC);
        else if (c < 2560) Ck[(size_t)rp * 512 + (c - 2048)] = (bf16_t)v;
        else               Cv[(size_t)rp * 512 + (c - 2560)] = (bf16_t)v;
      }
    }
  }
}

// ---------------------------------------------------------------------------
// k_gemmB: unchanged from round 10 (round-7 8-phase 256x256 body, locality
// XCD map, grid 256 = 1 clean wave).
// ---------------------------------------------------------------------------
#define LSLOT(B_, M_, H_) (lds + (((B_)*4 + (M_)*2 + (H_)) << 13))

#define STAGE_A(BUF, HF, T)                                                     \
  gload_lds16(aB + (size_t)((HF)*128) * 2048 + (T)*64, LSLOT(BUF, 0, HF) + wofs); \
  gload_lds16(aB + (size_t)((HF)*128 + 64) * 2048 + (T)*64,                     \
              LSLOT(BUF, 0, HF) + wofs + 4096);

#define STAGE_B(BUF, HF, T)                                                     \
  gload_lds16(bB + (size_t)((HF)*128) * 2048 + (T)*64, LSLOT(BUF, 1, HF) + wofs); \
  gload_lds16(bB + (size_t)((HF)*128 + 64) * 2048 + (T)*64,                     \
              LSLOT(BUF, 1, HF) + wofs + 4096);

#define LOAD_A(BUF, Q)                                                          \
  { const bf16_t* Ah = LSLOT(BUF, 0, wm) + ((Q)*32 + cl) * 64;                  \
    DSR(Ah + ((g16 * 8) ^ swz8), af[0][0]);                                     \
    DSR(Ah + ((32 + g16 * 8) ^ swz8), af[0][1]);                                \
    DSR(Ah + 1024 + ((g16 * 8) ^ swz8), af[1][0]);                              \
    DSR(Ah + 1024 + ((32 + g16 * 8) ^ swz8), af[1][1]); }

#define LOAD_B(BUF)                                                             \
  { const bf16_t* Bh = LSLOT(BUF, 1, wn >> 1);                                  \
    _Pragma("unroll") for (int ni = 0; ni < 4; ++ni) {                          \
      const bf16_t* Br = Bh + ((wn & 1) * 64 + ni * 16 + cl) * 64;              \
      DSR(Br + ((g16 * 8) ^ swz8), bfr[ni][0]);                                 \
      DSR(Br + ((32 + g16 * 8) ^ swz8), bfr[ni][1]); } }

#define MFMA_QUAD(Q)                                                            \
  _Pragma("unroll") for (int kk = 0; kk < 2; ++kk)                              \
    _Pragma("unroll") for (int ni = 0; ni < 4; ++ni) {                          \
      acc[2*(Q)][ni]   = MFMA16(af[0][kk].b, bfr[ni][kk].b, acc[2*(Q)][ni]);    \
      acc[2*(Q)+1][ni] = MFMA16(af[1][kk].b, bfr[ni][kk].b, acc[2*(Q)+1][ni]); }

#define PH_MID(VM4)                                                             \
  if (VM4) asm volatile("s_waitcnt vmcnt(4)" ::: "memory");                     \
  __builtin_amdgcn_s_barrier();                                                 \
  asm volatile("s_waitcnt lgkmcnt(0)" ::: "memory");                            \
  SBAR;                                                                         \
  __builtin_amdgcn_s_setprio(1);

#define PH_END                                                                  \
  SBAR;                                                                         \
  __builtin_amdgcn_s_setprio(0);                                                \
  __builtin_amdgcn_s_barrier();

__global__ __launch_bounds__(512, 2) void k_gemmB(
    const bf16_t* __restrict__ A, const bf16_t* __restrict__ B0,
    float* __restrict__ Cf) {
  extern __shared__ bf16_t lds[];

  int bid = blockIdx.x;
  int s = bid >> 3;                 // 0..31
  int tm = (bid & 7) * 4 + (s >> 3);
  int tn = s & 7;
  const bf16_t* Bp = B0;
  int brow = tn << 8;

  int tid = threadIdx.x;
  int lane = tid & 63;
  int w = tid >> 6;
  int wm = w >> 2, wn = w & 3;
  int g16 = lane >> 4, cl = lane & 15;
  int swz8 = (cl & 7) << 3;
  int wofs = w << 9;

  int srow = tid >> 3;
  int lc = (((tid & 7) ^ (srow & 7)) << 3);
  const bf16_t* aB = A + (size_t)(tm * 256 + srow) * 2048 + lc;
  const bf16_t* bB = Bp + (size_t)(brow + srow) * 2048 + lc;

  f32x4 acc[8][4];
#pragma unroll
  for (int i = 0; i < 8; ++i)
#pragma unroll
    for (int j = 0; j < 4; ++j) acc[i][j] = (f32x4)(0.0f);

  STAGE_A(0, 0, 0); STAGE_A(0, 1, 0);
  STAGE_B(0, 0, 0); STAGE_B(0, 1, 0);
  STAGE_B(1, 0, 1); STAGE_B(1, 1, 1);
  asm volatile("s_waitcnt vmcnt(4)" ::: "memory");
  __builtin_amdgcn_s_barrier();

  for (int it2 = 0; it2 < 16; ++it2) {
    int t1 = 2 * it2 + 1;
    int tf = 2 * it2 + 2; if (tf > 31) tf = 31;
    int tg = 2 * it2 + 3; if (tg > 31) tg = 31;
    B128 af[2][2], bfr[4][2];
    STAGE_A(1, 0, t1);
    LOAD_B(0); LOAD_A(0, 0);
    PH_MID(0); MFMA_QUAD(0); PH_END;
    STAGE_A(1, 1, t1);
    LOAD_A(0, 1);
    PH_MID(0); MFMA_QUAD(1); PH_END;
    STAGE_B(0, 0, tf);
    LOAD_A(0, 2);
    PH_MID(0); MFMA_QUAD(2); PH_END;
    STAGE_B(0, 1, tf);
    LOAD_A(0, 3);
    PH_MID(1); MFMA_QUAD(3); PH_END;
    STAGE_A(0, 0, tf);
    LOAD_B(1); LOAD_A(1, 0);
    PH_MID(0); MFMA_QUAD(0); PH_END;
    STAGE_A(0, 1, tf);
    LOAD_A(1, 1);
    PH_MID(0); MFMA_QUAD(1); PH_END;
    STAGE_B(1, 0, tg);
    LOAD_A(1, 2);
    PH_MID(0); MFMA_QUAD(2); PH_END;
    STAGE_B(1, 1, tg);
    LOAD_A(1, 3);
    PH_MID(1); MFMA_QUAD(3); PH_END;
  }

#pragma unroll
  for (int mi = 0; mi < 8; ++mi) {
#pragma unroll
    for (int rr = 0; rr < 4; ++rr) {
      int r = tm * 256 + wm * 128 + mi * 16 + g16 * 4 + rr;
#pragma unroll
      for (int ni = 0; ni < 4; ++ni) {
        int c = tn * 256 + wn * 64 + ni * 16 + cl;
        Cf[(size_t)r * 2048 + c] = acc[mi][ni][rr];
      }
    }
  }
}

// m214-style swapped-QK^T flash attention (round-13 body, unchanged).
__global__ __launch_bounds__(256, 2) void k_attn(
    const bf16_t* __restrict__ Qp, const bf16_t* __restrict__ Kp,
    const bf16_t* __restrict__ Vp, bf16_t* __restrict__ O) {
  int bid = blockIdx.x;
  int qc = bid & 7;
  int h  = (bid >> 3) & 31;
  int n  = bid >> 8;
  int kvh = h >> 2;

  __shared__ bf16_t buf[2][8192];

  int tid = threadIdx.x, lane = tid & 63, w = tid >> 6;
  int l31 = lane & 31, hi = lane >> 5;
  int qrow_blk = n * 1024 + qc * 128;
  bf16_t* base = &buf[0][0];

#pragma unroll
  for (int r = 0; r < 4; ++r) {
    int ql = r * 32 + (tid >> 3);
    int cs = (tid & 7) << 4;
    int lc = (cs ^ ((ql & 7) << 4)) >> 1;
    gload_lds16(Qp + (size_t)(qrow_blk + ql) * 2048 + h * 64 + lc,
                base + r * 2048 + w * 512);
  }
  __syncthreads();
  bf16x8 qf[4];
  {
    int q = w * 32 + l31;
    const bf16_t* qrow = base + q * 64;
    int sw = (q & 7) << 4;
#pragma unroll
    for (int c = 0; c < 4; ++c)
      qf[c] = *(const bf16x8*)(qrow + (((c * 32 + hi * 16) ^ sw) >> 1));
  }
  __syncthreads();

  f32x16 oacc0 = (f32x16)(0.0f), oacc1 = (f32x16)(0.0f);
  float m_run = -1e30f, l_run = 0.0f;

  auto stageKV = [&](int t) {
    bf16_t* bp = &buf[t & 1][0];
    int kvb = n * 1024 + t * 64;
#pragma unroll
    for (int r = 0; r < 2; ++r) {
      int kv = r * 32 + (tid >> 3);
      int cs = (tid & 7) << 4;
      int lc = (cs ^ ((kv & 7) << 4)) >> 1;
      gload_lds16(Kp + (size_t)(kvb + kv) * 512 + kvh * 64 + lc,
                  bp + r * 2048 + w * 512);
    }
#pragma unroll
    for (int r = 0; r < 2; ++r) {
      int slot = r * 256 + tid;
      int sub = slot >> 3;
      int kb = sub >> 2, db = sub & 3;
      int j = (slot >> 1) & 3, hf = slot & 1;
      gload_lds16(Vp + (size_t)(kvb + kb * 4 + j) * 512 + kvh * 64 + db * 16 + hf * 8,
                  bp + 4096 + r * 2048 + w * 512);
    }
  };

  stageKV(0);
  for (int t = 0; t < 16; ++t) {
    __syncthreads();
    if (t < 15) stageKV(t + 1);
    const bf16_t* bp = &buf[t & 1][0];
    const bf16_t* Vs = bp + 4096;

#pragma unroll
    for (int s = 0; s < 2; ++s) {
      f32x16 st = (f32x16)(0.0f);
      {
        int kv = s * 32 + l31;
        const bf16_t* krow = bp + kv * 64;
        int sw = (kv & 7) << 4;
#pragma unroll
        for (int c = 0; c < 4; ++c) {
          bf16x8 kf = *(const bf16x8*)(krow + (((c * 32 + hi * 16) ^ sw) >> 1));
          st = MFMA32(kf, qf[c], st);
        }
      }
      // pmax via v_max3-friendly nesting: 5 triples + 2 triples + 1 max
      float p0 = fmaxf(fmaxf(st[0], st[1]), st[2]);
      float p1 = fmaxf(fmaxf(st[3], st[4]), st[5]);
      float p2 = fmaxf(fmaxf(st[6], st[7]), st[8]);
      float p3 = fmaxf(fmaxf(st[9], st[10]), st[11]);
      float p4 = fmaxf(fmaxf(st[12], st[13]), st[14]);
      float pmax = fmaxf(fmaxf(fmaxf(p0, p1), p2),
                         fmaxf(fmaxf(p3, p4), st[15]));
      pmax = fmaxf(pmax, __shfl_xor(pmax, 32));
      if (!__all(pmax <= m_run + 11.0f)) {
        float mnew = fmaxf(m_run, pmax);
        float resc = EXP2F(m_run - mnew);
        l_run *= resc;
#pragma unroll
        for (int e = 0; e < 16; ++e) { oacc0[e] *= resc; oacc1[e] *= resc; }
        m_run = mnew;
      }
      float rs = 0.0f;
      unsigned pw[8];
#pragma unroll
      for (int u = 0; u < 8; ++u) {
        float q0 = EXP2F(st[2 * u] - m_run);
        float q1 = EXP2F(st[2 * u + 1] - m_run);
        rs += q0 + q1;
        pw[u] = cvt_pk_bf16(q0, q1);
      }
      rs += __shfl_xor(rs, 32);
      l_run += rs;

#pragma unroll
      for (int c = 0; c < 2; ++c) {
        unsigned w2, w0, w3, w1;
        swap32(pw[c * 4 + 2], pw[c * 4 + 0], hi, w2, w0);
        swap32(pw[c * 4 + 3], pw[c * 4 + 1], hi, w3, w1);
        union { unsigned u[4]; bf16x8 v; } pa;
        pa.u[0] = w0; pa.u[1] = w1; pa.u[2] = w2; pa.u[3] = w3;
        int kb0 = s * 8 + c * 4 + hi * 2;
        int dbl = l31 >> 4;
        int cc8 = (l31 & 15) * 4;
        const bf16_t* p00 = Vs + (kb0 * 4 + dbl) * 64 + cc8;
        const bf16_t* p01 = Vs + ((kb0 + 1) * 4 + dbl) * 64 + cc8;
        const bf16_t* p10 = Vs + (kb0 * 4 + 2 + dbl) * 64 + cc8;
        const bf16_t* p11 = Vs + ((kb0 + 1) * 4 + 2 + dbl) * 64 + cc8;
        s16x4 t00 = tr_b16(p00), t01 = tr_b16(p01);
        s16x4 t10 = tr_b16(p10), t11 = tr_b16(p11);
        asm volatile("s_waitcnt lgkmcnt(0)" ::: "memory");
        __builtin_amdgcn_sched_barrier(0);
        union { s16x4 s4[2]; bf16x8 v; } vf0, vf1;
        vf0.s4[0] = t00; vf0.s4[1] = t01;
        vf1.s4[0] = t10; vf1.s4[1] = t11;
        oacc0 = MFMA32(pa.v, vf0.v, oacc0);
        oacc1 = MFMA32(pa.v, vf1.v, oacc1);
      }
    }
  }

  float linv = 1.0f / l_run;
#pragma unroll
  for (int r = 0; r < 16; ++r) {
    int qrw = (r & 3) + 8 * (r >> 2) + 4 * hi;
    float li = __shfl(linv, qrw);
    size_t orow = (size_t)(qrow_blk + w * 32 + qrw) * 2048 + h * 64 + l31;
    O[orow]      = (bf16_t)(oacc0[r] * li);
    O[orow + 32] = (bf16_t)(oacc1[r] * li);
  }
}

extern "C" void kernel_launch(void* const* d_in, const int* in_sizes, int n_in,
                              void* d_out, int out_size, void* d_ws, size_t ws_size,
                              hipStream_t stream) {
  const float* X  = (const float*)d_in[0];
  const float* Wq = (const float*)d_in[1];
  const float* Wk = (const float*)d_in[2];
  const float* Wv = (const float*)d_in[3];
  const float* Wo = (const float*)d_in[4];
  float* out = (float*)d_out;

  char* ws = (char*)d_ws;
  const size_t MB = 1024 * 1024;
  bf16_t* Xb  = (bf16_t*)(ws + 0);
  bf16_t* WqT = (bf16_t*)(ws + 32 * MB);
  bf16_t* WkT = (bf16_t*)(ws + 40 * MB);
  bf16_t* WvT = (bf16_t*)(ws + 42 * MB);
  bf16_t* WoT = (bf16_t*)(ws + 44 * MB);
  bf16_t* Qp  = (bf16_t*)(ws + 52 * MB);
  bf16_t* Kp  = (bf16_t*)(ws + 84 * MB);
  bf16_t* Vp  = (bf16_t*)(ws + 92 * MB);
  bf16_t* Ob  = (bf16_t*)(ws + 100 * MB);

  hipFuncSetAttribute(reinterpret_cast<const void*>(&k_gemmA),
                      hipFuncAttributeMaxDynamicSharedMemorySize, 147456);
  hipFuncSetAttribute(reinterpret_cast<const void*>(&k_gemmB),
                      hipFuncAttributeMaxDynamicSharedMemorySize, 131072);

  k_convert<<<16384, 256, 0, stream>>>(X, Xb, 4194304);
  k_transpose<<<dim3(32, 32), 256, 0, stream>>>(Wq, WqT, 2048, 2048);
  k_transpose<<<dim3(8, 32), 256, 0, stream>>>(Wk, WkT, 2048, 512);
  k_transpose<<<dim3(8, 32), 256, 0, stream>>>(Wv, WvT, 2048, 512);
  k_transpose<<<dim3(32, 32), 256, 0, stream>>>(Wo, WoT, 2048, 2048);

  k_gemmA<<<768, 512, 147456, stream>>>(Xb, WqT, WkT, WvT, Qp, Kp, Vp);
  k_attn<<<2048, 256, 0, stream>>>(Qp, Kp, Vp, Ob);
  k_gemmB<<<256, 512, 131072, stream>>>(Ob, WoT, out);
}